// Round 7
// baseline (1591.394 us; speedup 1.0000x reference)
//
#include <hip/hip_runtime.h>
#include <hip/hip_bf16.h>

#define NNODE 4096
#define NPB   1024
#define KNEI  16

__device__ __forceinline__ float siluf(float x){ return x / (1.0f + expf(-x)); }

// ---------------- LDS layout (floats), peak 9664 floats = 38656 B ----------------
#define O_CRD  0     /* 3072: staged coords (KNN+GEO) */
#define O_ES   0     /* 2112: src emb l=0 (logits)     */
#define O_ED   2112  /* 128 : dst emb l=0              */
#define O_QD   2240  /* 64  : dst query                */
#define O_LG   2304  /* 128 : logits                   */
#define O_SX   2432  /* 16  : softmax scratch          */
#define O_AT   2448  /* 128 : attention (persists)     */
#define O_XS   0     /* 1188: rotated src emb (Wv)     */
#define O_HF   0     /* 2336: gated FFN hidden         */
#define O_RB   3072  /* 2112: rbf                      */
#define O_AG   3072  /* 1152: aggregated message       */
#define O_RED  4224  /* 1152: rms reduction            */
#define O_SS   5376  /* 16  : rms denominators         */
#define O_HL   5440  /* 1188: h = rmsnorm(x)*g2        */
#define O_HD   5184  /* 2112: edge-MLP hidden          */
#define O_EH   7296  /* 2112: edge_h (persists to Wv)  */
#define O_MS   7296  /* 256 : mish(cond) (film phase)  */
#define O_RR   9408  /* 192 : 16 x (R[9], len, valid)  */
#define O_KI   9600  /* 16 ints: knn indices           */
#define O_KD   9616  /* 16 : knn d2                    */
#define O_MG   9632  /* 2 f + 2 i: wave merge          */

__global__ __launch_bounds__(128) void k_node(
    const float* __restrict__ coord,
    const float* __restrict__ emb,
    const float* __restrict__ cond,
    const float* __restrict__ We1, const float* __restrict__ be1,
    const float* __restrict__ We2, const float* __restrict__ be2,
    const float* __restrict__ Wsrc, const float* __restrict__ Wdst,
    const float* __restrict__ wa,
    const float* __restrict__ Wv, const float* __restrict__ Wo,
    const float* __restrict__ g1, const float* __restrict__ g2,
    const float* __restrict__ Wg, const float* __restrict__ Wf1,
    const float* __restrict__ Wf2,
    const float* __restrict__ Wfilm, const float* __restrict__ bfilm,
    float* __restrict__ out){
  __shared__ __align__(16) float S[9664];
  int* Si = (int*)S;
  const int n = blockIdx.x;
  const int t = threadIdx.x;
  const int base = n & ~(NPB - 1);
  const int self = n - base;

  // ---- P0: KNN over this node's batch of 1024 candidates ----
  for(int idx = t; idx < 3072; idx += 128) S[O_CRD + idx] = coord[base*3 + idx];
  __syncthreads();
  const float cx = S[O_CRD + self*3+0];
  const float cy = S[O_CRD + self*3+1];
  const float cz = S[O_CRD + self*3+2];
  float d2a[8]; int ida[8];
  for(int q=0;q<8;q++){
    int j = t*8 + q;
    float dx = __fsub_rn(S[O_CRD + j*3+0], cx);
    float dy = __fsub_rn(S[O_CRD + j*3+1], cy);
    float dz = __fsub_rn(S[O_CRD + j*3+2], cz);
    float d2 = __fadd_rn(__fadd_rn(__fmul_rn(dx,dx), __fmul_rn(dy,dy)), __fmul_rn(dz,dz));
    if(j == self) d2 = 3e38f;
    d2a[q] = d2; ida[q] = j;
  }
  for(int r=0;r<16;r++){
    float bd = d2a[0]; int bi = ida[0];
    for(int q=1;q<8;q++){
      bool bet = (d2a[q] < bd) || (d2a[q] == bd && ida[q] < bi);
      if(bet){ bd = d2a[q]; bi = ida[q]; }
    }
    for(int s=1;s<64;s<<=1){
      float od = __shfl_xor(bd, s, 64);
      int   oi = __shfl_xor(bi, s, 64);
      bool bet = (od < bd) || (od == bd && oi < bi);
      if(bet){ bd = od; bi = oi; }
    }
    if((t & 63) == 0){ S[O_MG + (t>>6)] = bd; Si[O_MG + 2 + (t>>6)] = bi; }
    __syncthreads();
    float d0 = S[O_MG+0], d1 = S[O_MG+1];
    int  i0 = Si[O_MG+2], i1 = Si[O_MG+3];
    bool take1 = (d1 < d0) || (d1 == d0 && i1 < i0);
    float wd = take1 ? d1 : d0;
    int   wi = take1 ? i1 : i0;
    if(t == 0){ Si[O_KI + r] = wi; S[O_KD + r] = wd; }
    for(int q=0;q<8;q++) if(ida[q] == wi) d2a[q] = 3e38f;
    __syncthreads();
  }

  // ---- P1: edge geometry (R, len, valid), threads 0..15 ----
  if(t < 16){
    int ls = Si[O_KI + t];
    float vx = __fsub_rn(S[O_CRD + ls*3+0], cx);
    float vy = __fsub_rn(S[O_CRD + ls*3+1], cy);
    float vz = __fsub_rn(S[O_CRD + ls*3+2], cz);
    float nrm = __fsqrt_rn(S[O_KD + t]);
    float den = __fadd_rn(nrm, 1e-12f);
    float nx0 = vx / den, nx1 = vy / den, nx2 = vz / den;
    float rx, ry, rz;
    if(fabsf(nx0) < 0.9f){ rx=1.f; ry=0.f; rz=0.f; } else { rx=0.f; ry=1.f; rz=0.f; }
    float zx = __fsub_rn(__fmul_rn(nx1,rz), __fmul_rn(nx2,ry));
    float zy = __fsub_rn(__fmul_rn(nx2,rx), __fmul_rn(nx0,rz));
    float zz = __fsub_rn(__fmul_rn(nx0,ry), __fmul_rn(nx1,rx));
    float zs = __fadd_rn(__fadd_rn(__fmul_rn(zx,zx), __fmul_rn(zy,zy)), __fmul_rn(zz,zz));
    float zn = __fadd_rn(__fsqrt_rn(zs), 1e-12f);
    zx = zx / zn; zy = zy / zn; zz = zz / zn;
    float yx = __fsub_rn(__fmul_rn(zy,nx2), __fmul_rn(zz,nx1));
    float yy = __fsub_rn(__fmul_rn(zz,nx0), __fmul_rn(zx,nx2));
    float yz = __fsub_rn(__fmul_rn(zx,nx1), __fmul_rn(zy,nx0));
    float* R = &S[O_RR + t*12];
    R[0]=zx; R[1]=zy; R[2]=zz;
    R[3]=nx0; R[4]=nx1; R[5]=nx2;
    R[6]=yx; R[7]=yy; R[8]=yz;
    R[9]=nrm;
    R[10]=(nrm <= 3.0f) ? 1.0f : 0.0f;
  }
  __syncthreads();

  // ---- P2: stage src/dst l=0 embeddings (overwrites coord region) ----
  for(int idx = t; idx < 2048; idx += 128){
    int e = idx >> 7, c = idx & 127;
    int src = base + Si[O_KI + e];
    S[O_ES + e*132 + c] = emb[(size_t)src*1152 + c];
  }
  S[O_ED + t] = emb[(size_t)n*1152 + t];
  __syncthreads();

  // ---- P3: qd = dst0 @ Wdst (threads 0..63) ----
  if(t < 64){
    float acc = 0.f;
    for(int c=0;c<128;c++) acc += S[O_ED + c] * Wdst[c*64 + t];
    S[O_QD + t] = acc;
  }
  __syncthreads();

  // ---- P4: logits (wave wv handles edges wv*8..wv*8+7) ----
  {
    int wv = t >> 6;
    int ha = t & 63;
    float acc8[8];
    for(int k=0;k<8;k++) acc8[k] = 0.f;
    for(int c=0;c<128;c++){
      float w = Wsrc[c*64 + ha];
      #pragma unroll
      for(int k=0;k<8;k++) acc8[k] += S[O_ES + (wv*8+k)*132 + c] * w;
    }
    float qd = S[O_QD + ha];
    float wav = wa[ha];
    for(int k=0;k<8;k++){
      float s = siluf(acc8[k] + qd) * wav;
      s += __shfl_xor(s, 1, 64);
      s += __shfl_xor(s, 2, 64);
      s += __shfl_xor(s, 4, 64);
      if((ha & 7) == 0){
        int e = wv*8 + k;
        float v = S[O_RR + e*12 + 10];
        S[O_LG + e*8 + (ha>>3)] = (v > 0.5f) ? s : -1e9f;
      }
    }
  }
  __syncthreads();

  // ---- P5: softmax per head over 16 edges ----
  if(t < 8){
    float m = -3e38f;
    for(int r=0;r<16;r++) m = fmaxf(m, S[O_LG + r*8 + t]);
    S[O_SX + t] = m;
  }
  __syncthreads();
  {
    float ex = expf(S[O_LG + t] - S[O_SX + (t & 7)]);
    __syncthreads();
    S[O_LG + t] = ex;
    __syncthreads();
    if(t < 8){
      float d = 0.f;
      for(int r=0;r<16;r++) d += S[O_LG + r*8 + t];
      S[O_SX + 8 + t] = d;
    }
    __syncthreads();
    S[O_AT + t] = ex / (S[O_SX + 8 + (t & 7)] + 1e-9f);
  }
  __syncthreads();

  // ---- P6: rbf ----
  {
    const float step = 3.0f/127.0f;
    const float sigma = 3.0f/128.0f;
    for(int idx = t; idx < 2048; idx += 128){
      int e = idx >> 7, i = idx & 127;
      float d = (S[O_RR + e*12 + 9] - step*(float)i) / sigma;
      S[O_RB + e*132 + i] = expf(-0.5f*d*d);
    }
  }
  __syncthreads();

  // ---- P7: hid = silu(rbf @ We1 + b1); thread t = column, all 16 edges ----
  {
    float acc16[16];
    for(int e=0;e<16;e++) acc16[e] = 0.f;
    for(int i=0;i<128;i++){
      float w = We1[i*128 + t];
      #pragma unroll
      for(int e=0;e<16;e++) acc16[e] += S[O_RB + e*132 + i] * w;
    }
    float b = be1[t];
    for(int e=0;e<16;e++) S[O_HD + e*132 + t] = siluf(acc16[e] + b);
  }
  __syncthreads();

  // ---- P8: eh = hid @ We2 + b2 ----
  {
    float acc16[16];
    for(int e=0;e<16;e++) acc16[e] = 0.f;
    for(int i=0;i<128;i++){
      float w = We2[i*128 + t];
      #pragma unroll
      for(int e=0;e<16;e++) acc16[e] += S[O_HD + e*132 + i] * w;
    }
    float b = be2[t];
    for(int e=0;e<16;e++) S[O_EH + e*132 + t] = acc16[e] + b;
  }
  __syncthreads();

  // ---- P9: per-edge rotate -> @Wv -> scale -> inv-rotate -> accumulate ----
  float acc[9];
  for(int l=0;l<9;l++) acc[l] = 0.f;
  for(int e=0;e<16;e++){
    int src = base + Si[O_KI + e];
    float R0=S[O_RR+e*12+0],R1=S[O_RR+e*12+1],R2=S[O_RR+e*12+2];
    float R3=S[O_RR+e*12+3],R4=S[O_RR+e*12+4],R5=S[O_RR+e*12+5];
    float R6=S[O_RR+e*12+6],R7=S[O_RR+e*12+7],R8=S[O_RR+e*12+8];
    float a[9];
    for(int l=0;l<9;l++) a[l] = emb[(size_t)src*1152 + l*128 + t];
    S[O_XS + 0*132 + t] = a[0];
    S[O_XS + 1*132 + t] = R0*a[1] + R1*a[2] + R2*a[3];
    S[O_XS + 2*132 + t] = R3*a[1] + R4*a[2] + R5*a[3];
    S[O_XS + 3*132 + t] = R6*a[1] + R7*a[2] + R8*a[3];
    for(int l=4;l<9;l++) S[O_XS + l*132 + t] = a[l];
    __syncthreads();
    float tmp[9];
    for(int l=0;l<9;l++) tmp[l] = 0.f;
    for(int i=0;i<128;i++){
      float w = Wv[i*128 + t];
      #pragma unroll
      for(int l=0;l<9;l++) tmp[l] += S[O_XS + l*132 + i] * w;
    }
    float sc = S[O_EH + e*132 + t] * S[O_AT + e*8 + (t>>4)];
    for(int l=0;l<9;l++) tmp[l] *= sc;
    acc[0] += tmp[0];
    acc[1] += R0*tmp[1] + R3*tmp[2] + R6*tmp[3];
    acc[2] += R1*tmp[1] + R4*tmp[2] + R7*tmp[3];
    acc[3] += R2*tmp[1] + R5*tmp[2] + R8*tmp[3];
    for(int l=4;l<9;l++) acc[l] += tmp[l];
    __syncthreads();
  }
  for(int l=0;l<9;l++) S[O_AG + l*128 + t] = acc[l];
  __syncthreads();

  // ---- P10: x = emb + agg @ Wo ; rmsnorm*g2 -> HL ----
  float x[9];
  for(int l=0;l<9;l++) x[l] = 0.f;
  for(int i=0;i<128;i++){
    float w = Wo[i*128 + t];
    #pragma unroll
    for(int l=0;l<9;l++) x[l] += S[O_AG + l*128 + i] * w;
  }
  for(int l=0;l<9;l++){
    x[l] += emb[(size_t)n*1152 + l*128 + t];
    S[O_RED + l*128 + t] = x[l]*x[l];
  }
  __syncthreads();
  if(t < 9){
    float s = 0.f;
    for(int i=0;i<128;i++) s += S[O_RED + t*128 + i];
    S[O_SS + t] = sqrtf(s/128.f + 1e-6f);
  }
  __syncthreads();
  {
    float g2c = g2[t];
    for(int l=0;l<9;l++) S[O_HL + l*132 + t] = x[l]/S[O_SS + l]*g2c;
  }
  __syncthreads();

  // ---- P11: gate + hf = (h @ Wf1)*gate -> HF ----
  {
    float ga0 = 0.f, ga1 = 0.f;
    for(int c=0;c<128;c++){
      float h0 = S[O_HL + c];
      ga0 += h0 * Wg[c*256 + t];
      ga1 += h0 * Wg[c*256 + t + 128];
    }
    float gate0 = siluf(ga0), gate1 = siluf(ga1);
    float f0[9], f1[9];
    for(int l=0;l<9;l++){ f0[l]=0.f; f1[l]=0.f; }
    for(int c=0;c<128;c++){
      float w0 = Wf1[c*256 + t];
      float w1 = Wf1[c*256 + t + 128];
      #pragma unroll
      for(int l=0;l<9;l++){
        float h = S[O_HL + l*132 + c];
        f0[l] += h*w0;
        f1[l] += h*w1;
      }
    }
    __syncthreads();
    for(int l=0;l<9;l++){
      S[O_HF + l*260 + t]       = f0[l]*gate0;
      S[O_HF + l*260 + t + 128] = f1[l]*gate1;
    }
  }
  __syncthreads();

  // ---- P12: x += hf @ Wf2 ----
  for(int f=0;f<256;f++){
    float w = Wf2[f*128 + t];
    #pragma unroll
    for(int l=0;l<9;l++) x[l] += S[O_HF + l*260 + f] * w;
  }
  __syncthreads();

  // ---- P13: final rmsnorm ----
  for(int l=0;l<9;l++) S[O_RED + l*128 + t] = x[l]*x[l];
  __syncthreads();
  if(t < 9){
    float s = 0.f;
    for(int i=0;i<128;i++) s += S[O_RED + t*128 + i];
    S[O_SS + t] = sqrtf(s/128.f + 1e-6f);
  }
  __syncthreads();

  // ---- P14: film (per-node, 18 needed columns) + store (f32!) ----
  {
    int b = n >> 10;
    for(int k=0;k<2;k++){
      float xx = cond[b*256 + t + k*128];
      float sp = fmaxf(xx, 0.f) + log1pf(expf(-fabsf(xx)));
      S[O_MS + t + k*128] = xx * tanhf(sp);
    }
  }
  __syncthreads();
  {
    float g1c = g1[t];
    for(int l=0;l<9;l++){
      int j = l*128 + t;
      float w  = bfilm[j];
      float bi = bfilm[1152 + j];
      for(int i=0;i<256;i++){
        float m = S[O_MS + i];
        w  += m * Wfilm[i*2304 + j];
        bi += m * Wfilm[i*2304 + 1152 + j];
      }
      float y = x[l]/S[O_SS + l]*g1c;
      out[12288 + (size_t)n*1152 + j] = y*w + bi;   // f32 store
    }
  }
}

// ---------- K2: coords (exact f32 copy) + batch (= n>>10, f32) ----------
__global__ __launch_bounds__(256) void k_copy(const float* __restrict__ coord,
                                              float* __restrict__ out){
  int i = blockIdx.x*256 + threadIdx.x;
  if(i < 12288) out[i] = coord[i];
  int n = i - 12288;
  if(n >= 0 && n < 4096) out[12288 + 4718592 + n] = (float)(n >> 10);
}

extern "C" void kernel_launch(void* const* d_in, const int* in_sizes, int n_in,
                              void* d_out, int out_size, void* d_ws, size_t ws_size,
                              hipStream_t stream) {
  const float* coord = (const float*)d_in[0];
  const float* emb   = (const float*)d_in[1];
  const float* cond  = (const float*)d_in[3];
  const float* We1   = (const float*)d_in[4];
  const float* be1   = (const float*)d_in[5];
  const float* We2   = (const float*)d_in[6];
  const float* be2   = (const float*)d_in[7];
  const float* Wsrc  = (const float*)d_in[8];
  const float* Wdst  = (const float*)d_in[9];
  const float* wa    = (const float*)d_in[10];
  const float* Wv    = (const float*)d_in[11];
  const float* Wo    = (const float*)d_in[12];
  const float* g1    = (const float*)d_in[13];
  const float* g2    = (const float*)d_in[14];
  const float* Wg    = (const float*)d_in[15];
  const float* Wf1   = (const float*)d_in[16];
  const float* Wf2   = (const float*)d_in[17];
  const float* Wfilm = (const float*)d_in[18];
  const float* bfilm = (const float*)d_in[19];

  float* outf = (float*)d_out;

  k_node<<<NNODE, 128, 0, stream>>>(coord, emb, cond,
                                    We1, be1, We2, be2, Wsrc, Wdst, wa,
                                    Wv, Wo, g1, g2, Wg, Wf1, Wf2,
                                    Wfilm, bfilm, outf);
  k_copy<<<64, 256, 0, stream>>>(coord, outf);
}

// Round 8
// 1446.035 us; speedup vs baseline: 1.1005x; 1.1005x over previous
//
#include <hip/hip_runtime.h>
#include <hip/hip_bf16.h>

#define NNODE 4096
#define NPB   1024
#define KNEI  16

__device__ __forceinline__ float siluf(float x){ return x / (1.0f + expf(-x)); }

// ---------------- LDS layout (floats), peak 7680 floats = 30720 B -> 5 blocks/CU ----------------
// Region A: 0..3072    CRD(P0-1) | ES/ED/QD/LG/SX(P2-5) | RB(P6-7) | XS(P9) | RED(P10,P13) | HF(P11-12)
// Region B: 3072..5184 HD(P7-8) | AG(P9-10)
// Region C: 5184..7296 EH(P8-9) | HL(P10-11)
// Region D: 7296..7680 AT, RR, KI, KD, MG, SS (long-lived smalls)
#define O_CRD  0
#define O_ES   0
#define O_ED   2112
#define O_QD   2240
#define O_LG   2304
#define O_SX   2432
#define O_RB   0
#define O_XS   0
#define O_RED  0
#define O_HF   0
#define O_HD   3072
#define O_AG   3072
#define O_EH   5184
#define O_HL   5184
#define O_AT   7296  /* 128 */
#define O_RR   7424  /* 192: 16 x (R[9], len, valid, pad) */
#define O_KI   7616  /* 16 ints */
#define O_KD   7632  /* 16 */
#define O_MG   7648  /* 2f + 2i */
#define O_SS   7652  /* 16 */

// ---------- K0: film = mish(cond) @ Wfilm + bfilm -> d_ws (4 x 2304 f32) ----------
__global__ __launch_bounds__(256) void k_film(const float* __restrict__ cond,
                                              const float* __restrict__ Wfilm,
                                              const float* __restrict__ bfilm,
                                              float* __restrict__ filmG){
  __shared__ float mL[256];
  int b = blockIdx.y;
  int t = threadIdx.x;
  int j = blockIdx.x*256 + t;
  float x = cond[b*256 + t];
  float sp = fmaxf(x, 0.f) + log1pf(expf(-fabsf(x)));
  mL[t] = x * tanhf(sp);
  __syncthreads();
  if(j >= 2304) return;
  float acc = bfilm[j];
  for(int i=0;i<256;i++) acc += mL[i] * Wfilm[i*2304 + j];
  filmG[b*2304 + j] = acc;
}

__global__ __launch_bounds__(128) void k_node(
    const float* __restrict__ coord,
    const float* __restrict__ emb,
    const float* __restrict__ We1, const float* __restrict__ be1,
    const float* __restrict__ We2, const float* __restrict__ be2,
    const float* __restrict__ Wsrc, const float* __restrict__ Wdst,
    const float* __restrict__ wa,
    const float* __restrict__ Wv, const float* __restrict__ Wo,
    const float* __restrict__ g1, const float* __restrict__ g2,
    const float* __restrict__ Wg, const float* __restrict__ Wf1,
    const float* __restrict__ Wf2,
    const float* __restrict__ filmG,
    float* __restrict__ out){
  __shared__ __align__(16) float S[7680];
  int* Si = (int*)S;
  const int n = blockIdx.x;
  const int t = threadIdx.x;
  const int base = n & ~(NPB - 1);
  const int self = n - base;

  // ---- P0: KNN over this node's batch of 1024 candidates ----
  for(int idx = t; idx < 3072; idx += 128) S[O_CRD + idx] = coord[base*3 + idx];
  __syncthreads();
  const float cx = S[O_CRD + self*3+0];
  const float cy = S[O_CRD + self*3+1];
  const float cz = S[O_CRD + self*3+2];
  float d2a[8]; int ida[8];
  for(int q=0;q<8;q++){
    int j = t*8 + q;
    float dx = __fsub_rn(S[O_CRD + j*3+0], cx);
    float dy = __fsub_rn(S[O_CRD + j*3+1], cy);
    float dz = __fsub_rn(S[O_CRD + j*3+2], cz);
    float d2 = __fadd_rn(__fadd_rn(__fmul_rn(dx,dx), __fmul_rn(dy,dy)), __fmul_rn(dz,dz));
    if(j == self) d2 = 3e38f;
    d2a[q] = d2; ida[q] = j;
  }
  for(int r=0;r<16;r++){
    float bd = d2a[0]; int bi = ida[0];
    for(int q=1;q<8;q++){
      bool bet = (d2a[q] < bd) || (d2a[q] == bd && ida[q] < bi);
      if(bet){ bd = d2a[q]; bi = ida[q]; }
    }
    for(int s=1;s<64;s<<=1){
      float od = __shfl_xor(bd, s, 64);
      int   oi = __shfl_xor(bi, s, 64);
      bool bet = (od < bd) || (od == bd && oi < bi);
      if(bet){ bd = od; bi = oi; }
    }
    if((t & 63) == 0){ S[O_MG + (t>>6)] = bd; Si[O_MG + 2 + (t>>6)] = bi; }
    __syncthreads();
    float d0 = S[O_MG+0], d1 = S[O_MG+1];
    int  i0 = Si[O_MG+2], i1 = Si[O_MG+3];
    bool take1 = (d1 < d0) || (d1 == d0 && i1 < i0);
    float wd = take1 ? d1 : d0;
    int   wi = take1 ? i1 : i0;
    if(t == 0){ Si[O_KI + r] = wi; S[O_KD + r] = wd; }
    for(int q=0;q<8;q++) if(ida[q] == wi) d2a[q] = 3e38f;
    __syncthreads();
  }

  // ---- P1: edge geometry (R, len, valid), threads 0..15 ----
  if(t < 16){
    int ls = Si[O_KI + t];
    float vx = __fsub_rn(S[O_CRD + ls*3+0], cx);
    float vy = __fsub_rn(S[O_CRD + ls*3+1], cy);
    float vz = __fsub_rn(S[O_CRD + ls*3+2], cz);
    float nrm = __fsqrt_rn(S[O_KD + t]);
    float den = __fadd_rn(nrm, 1e-12f);
    float nx0 = vx / den, nx1 = vy / den, nx2 = vz / den;
    float rx, ry, rz;
    if(fabsf(nx0) < 0.9f){ rx=1.f; ry=0.f; rz=0.f; } else { rx=0.f; ry=1.f; rz=0.f; }
    float zx = __fsub_rn(__fmul_rn(nx1,rz), __fmul_rn(nx2,ry));
    float zy = __fsub_rn(__fmul_rn(nx2,rx), __fmul_rn(nx0,rz));
    float zz = __fsub_rn(__fmul_rn(nx0,ry), __fmul_rn(nx1,rx));
    float zs = __fadd_rn(__fadd_rn(__fmul_rn(zx,zx), __fmul_rn(zy,zy)), __fmul_rn(zz,zz));
    float zn = __fadd_rn(__fsqrt_rn(zs), 1e-12f);
    zx = zx / zn; zy = zy / zn; zz = zz / zn;
    float yx = __fsub_rn(__fmul_rn(zy,nx2), __fmul_rn(zz,nx1));
    float yy = __fsub_rn(__fmul_rn(zz,nx0), __fmul_rn(zx,nx2));
    float yz = __fsub_rn(__fmul_rn(zx,nx1), __fmul_rn(zy,nx0));
    float* R = &S[O_RR + t*12];
    R[0]=zx; R[1]=zy; R[2]=zz;
    R[3]=nx0; R[4]=nx1; R[5]=nx2;
    R[6]=yx; R[7]=yy; R[8]=yz;
    R[9]=nrm;
    R[10]=(nrm <= 3.0f) ? 1.0f : 0.0f;
  }
  __syncthreads();

  // ---- P2: stage src l=0 rows (f4) + dst l=0 row ----
  for(int it=0; it<4; it++){
    int vid = it*128 + t;          // 512 float4 = 16 edges x 32 vec
    int e = vid >> 5, c4 = vid & 31;
    int src = base + Si[O_KI + e];
    *(float4*)&S[O_ES + e*132 + c4*4] = *(const float4*)&emb[(size_t)src*1152 + c4*4];
  }
  S[O_ED + t] = emb[(size_t)n*1152 + t];
  __syncthreads();

  // ---- P3: qd = dst0 @ Wdst (threads 0..63) ----
  if(t < 64){
    float acc = 0.f;
    for(int c4=0;c4<32;c4++){
      float4 ev = *(const float4*)&S[O_ED + c4*4];
      acc += ev.x * Wdst[(c4*4+0)*64 + t];
      acc += ev.y * Wdst[(c4*4+1)*64 + t];
      acc += ev.z * Wdst[(c4*4+2)*64 + t];
      acc += ev.w * Wdst[(c4*4+3)*64 + t];
    }
    S[O_QD + t] = acc;
  }
  __syncthreads();

  // ---- P4: logits (wave wv handles edges wv*8..wv*8+7) ----
  {
    int wv = t >> 6;
    int ha = t & 63;
    float acc8[8];
    #pragma unroll
    for(int k=0;k<8;k++) acc8[k] = 0.f;
    for(int c4=0;c4<32;c4++){
      float w0 = Wsrc[(c4*4+0)*64 + ha];
      float w1 = Wsrc[(c4*4+1)*64 + ha];
      float w2 = Wsrc[(c4*4+2)*64 + ha];
      float w3 = Wsrc[(c4*4+3)*64 + ha];
      #pragma unroll
      for(int k=0;k<8;k++){
        float4 es = *(const float4*)&S[O_ES + (wv*8+k)*132 + c4*4];
        acc8[k] += es.x*w0 + es.y*w1 + es.z*w2 + es.w*w3;
      }
    }
    float qd = S[O_QD + ha];
    float wav = wa[ha];
    #pragma unroll
    for(int k=0;k<8;k++){
      float s = siluf(acc8[k] + qd) * wav;
      s += __shfl_xor(s, 1, 64);
      s += __shfl_xor(s, 2, 64);
      s += __shfl_xor(s, 4, 64);
      if((ha & 7) == 0){
        int e = wv*8 + k;
        float v = S[O_RR + e*12 + 10];
        S[O_LG + e*8 + (ha>>3)] = (v > 0.5f) ? s : -1e9f;
      }
    }
  }
  __syncthreads();

  // ---- P5: softmax per head over 16 edges ----
  if(t < 8){
    float m = -3e38f;
    for(int r=0;r<16;r++) m = fmaxf(m, S[O_LG + r*8 + t]);
    S[O_SX + t] = m;
  }
  __syncthreads();
  {
    float ex = expf(S[O_LG + t] - S[O_SX + (t & 7)]);
    __syncthreads();
    S[O_LG + t] = ex;
    __syncthreads();
    if(t < 8){
      float d = 0.f;
      for(int r=0;r<16;r++) d += S[O_LG + r*8 + t];
      S[O_SX + 8 + t] = d;
    }
    __syncthreads();
    S[O_AT + t] = ex / (S[O_SX + 8 + (t & 7)] + 1e-9f);
  }
  __syncthreads();

  // ---- P6: rbf (overwrites ES region) ----
  {
    const float step = 3.0f/127.0f;
    const float sigma = 3.0f/128.0f;
    for(int idx = t; idx < 2048; idx += 128){
      int e = idx >> 7, i = idx & 127;
      float d = (S[O_RR + e*12 + 9] - step*(float)i) / sigma;
      S[O_RB + e*132 + i] = expf(-0.5f*d*d);
    }
  }
  __syncthreads();

  // ---- P7: hid = silu(rbf @ We1 + b1); thread t = column, all 16 edges ----
  {
    float acc16[16];
    #pragma unroll
    for(int e=0;e<16;e++) acc16[e] = 0.f;
    for(int i4=0;i4<32;i4++){
      float w0 = We1[(i4*4+0)*128 + t];
      float w1 = We1[(i4*4+1)*128 + t];
      float w2 = We1[(i4*4+2)*128 + t];
      float w3 = We1[(i4*4+3)*128 + t];
      #pragma unroll
      for(int e=0;e<16;e++){
        float4 r = *(const float4*)&S[O_RB + e*132 + i4*4];
        acc16[e] += r.x*w0 + r.y*w1 + r.z*w2 + r.w*w3;
      }
    }
    float b = be1[t];
    #pragma unroll
    for(int e=0;e<16;e++) S[O_HD + e*132 + t] = siluf(acc16[e] + b);
  }
  __syncthreads();

  // ---- P8: eh = hid @ We2 + b2 ----
  {
    float acc16[16];
    #pragma unroll
    for(int e=0;e<16;e++) acc16[e] = 0.f;
    for(int i4=0;i4<32;i4++){
      float w0 = We2[(i4*4+0)*128 + t];
      float w1 = We2[(i4*4+1)*128 + t];
      float w2 = We2[(i4*4+2)*128 + t];
      float w3 = We2[(i4*4+3)*128 + t];
      #pragma unroll
      for(int e=0;e<16;e++){
        float4 h = *(const float4*)&S[O_HD + e*132 + i4*4];
        acc16[e] += h.x*w0 + h.y*w1 + h.z*w2 + h.w*w3;
      }
    }
    float b = be2[t];
    #pragma unroll
    for(int e=0;e<16;e++) S[O_EH + e*132 + t] = acc16[e] + b;
  }
  __syncthreads();

  // ---- P9: per-edge rotate -> @Wv -> scale -> inv-rotate -> accumulate ----
  float acc[9];
  #pragma unroll
  for(int l=0;l<9;l++) acc[l] = 0.f;
  for(int e=0;e<16;e++){
    int src = base + Si[O_KI + e];
    float R0=S[O_RR+e*12+0],R1=S[O_RR+e*12+1],R2=S[O_RR+e*12+2];
    float R3=S[O_RR+e*12+3],R4=S[O_RR+e*12+4],R5=S[O_RR+e*12+5];
    float R6=S[O_RR+e*12+6],R7=S[O_RR+e*12+7],R8=S[O_RR+e*12+8];
    float a[9];
    #pragma unroll
    for(int l=0;l<9;l++) a[l] = emb[(size_t)src*1152 + l*128 + t];
    S[O_XS + 0*132 + t] = a[0];
    S[O_XS + 1*132 + t] = R0*a[1] + R1*a[2] + R2*a[3];
    S[O_XS + 2*132 + t] = R3*a[1] + R4*a[2] + R5*a[3];
    S[O_XS + 3*132 + t] = R6*a[1] + R7*a[2] + R8*a[3];
    #pragma unroll
    for(int l=4;l<9;l++) S[O_XS + l*132 + t] = a[l];
    __syncthreads();
    float tmp[9];
    #pragma unroll
    for(int l=0;l<9;l++) tmp[l] = 0.f;
    for(int i4=0;i4<32;i4++){
      float w0 = Wv[(i4*4+0)*128 + t];
      float w1 = Wv[(i4*4+1)*128 + t];
      float w2 = Wv[(i4*4+2)*128 + t];
      float w3 = Wv[(i4*4+3)*128 + t];
      #pragma unroll
      for(int l=0;l<9;l++){
        float4 x4 = *(const float4*)&S[O_XS + l*132 + i4*4];
        tmp[l] += x4.x*w0 + x4.y*w1 + x4.z*w2 + x4.w*w3;
      }
    }
    float sc = S[O_EH + e*132 + t] * S[O_AT + e*8 + (t>>4)];
    #pragma unroll
    for(int l=0;l<9;l++) tmp[l] *= sc;
    acc[0] += tmp[0];
    acc[1] += R0*tmp[1] + R3*tmp[2] + R6*tmp[3];
    acc[2] += R1*tmp[1] + R4*tmp[2] + R7*tmp[3];
    acc[3] += R2*tmp[1] + R5*tmp[2] + R8*tmp[3];
    #pragma unroll
    for(int l=4;l<9;l++) acc[l] += tmp[l];
    __syncthreads();
  }
  #pragma unroll
  for(int l=0;l<9;l++) S[O_AG + l*128 + t] = acc[l];
  __syncthreads();

  // ---- P10: x = emb + agg @ Wo ; rmsnorm*g2 -> HL ----
  float x[9];
  #pragma unroll
  for(int l=0;l<9;l++) x[l] = 0.f;
  for(int i4=0;i4<32;i4++){
    float w0 = Wo[(i4*4+0)*128 + t];
    float w1 = Wo[(i4*4+1)*128 + t];
    float w2 = Wo[(i4*4+2)*128 + t];
    float w3 = Wo[(i4*4+3)*128 + t];
    #pragma unroll
    for(int l=0;l<9;l++){
      float4 a4 = *(const float4*)&S[O_AG + l*128 + i4*4];
      x[l] += a4.x*w0 + a4.y*w1 + a4.z*w2 + a4.w*w3;
    }
  }
  #pragma unroll
  for(int l=0;l<9;l++){
    x[l] += emb[(size_t)n*1152 + l*128 + t];
    S[O_RED + l*128 + t] = x[l]*x[l];
  }
  __syncthreads();
  if(t < 9){
    float s = 0.f;
    for(int i=0;i<128;i++) s += S[O_RED + t*128 + i];
    S[O_SS + t] = sqrtf(s/128.f + 1e-6f);
  }
  __syncthreads();
  {
    float g2c = g2[t];
    #pragma unroll
    for(int l=0;l<9;l++) S[O_HL + l*132 + t] = x[l]/S[O_SS + l]*g2c;
  }
  __syncthreads();

  // ---- P11: gate + hf = (h @ Wf1)*gate -> HF ----
  {
    float ga0 = 0.f, ga1 = 0.f;
    for(int c4=0;c4<32;c4++){
      float4 h4 = *(const float4*)&S[O_HL + c4*4];
      ga0 += h4.x*Wg[(c4*4+0)*256 + t] + h4.y*Wg[(c4*4+1)*256 + t]
           + h4.z*Wg[(c4*4+2)*256 + t] + h4.w*Wg[(c4*4+3)*256 + t];
      ga1 += h4.x*Wg[(c4*4+0)*256 + t + 128] + h4.y*Wg[(c4*4+1)*256 + t + 128]
           + h4.z*Wg[(c4*4+2)*256 + t + 128] + h4.w*Wg[(c4*4+3)*256 + t + 128];
    }
    float gate0 = siluf(ga0), gate1 = siluf(ga1);
    float f0[9], f1[9];
    #pragma unroll
    for(int l=0;l<9;l++){ f0[l]=0.f; f1[l]=0.f; }
    for(int c4=0;c4<32;c4++){
      float w0a = Wf1[(c4*4+0)*256 + t], w0b = Wf1[(c4*4+0)*256 + t + 128];
      float w1a = Wf1[(c4*4+1)*256 + t], w1b = Wf1[(c4*4+1)*256 + t + 128];
      float w2a = Wf1[(c4*4+2)*256 + t], w2b = Wf1[(c4*4+2)*256 + t + 128];
      float w3a = Wf1[(c4*4+3)*256 + t], w3b = Wf1[(c4*4+3)*256 + t + 128];
      #pragma unroll
      for(int l=0;l<9;l++){
        float4 h4 = *(const float4*)&S[O_HL + l*132 + c4*4];
        f0[l] += h4.x*w0a + h4.y*w1a + h4.z*w2a + h4.w*w3a;
        f1[l] += h4.x*w0b + h4.y*w1b + h4.z*w2b + h4.w*w3b;
      }
    }
    __syncthreads();   // HL reads done before HF overwrites region A
    #pragma unroll
    for(int l=0;l<9;l++){
      S[O_HF + l*260 + t]       = f0[l]*gate0;
      S[O_HF + l*260 + t + 128] = f1[l]*gate1;
    }
  }
  __syncthreads();

  // ---- P12: x += hf @ Wf2 ----
  for(int f4=0;f4<64;f4++){
    float w0 = Wf2[(f4*4+0)*128 + t];
    float w1 = Wf2[(f4*4+1)*128 + t];
    float w2 = Wf2[(f4*4+2)*128 + t];
    float w3 = Wf2[(f4*4+3)*128 + t];
    #pragma unroll
    for(int l=0;l<9;l++){
      float4 h4 = *(const float4*)&S[O_HF + l*260 + f4*4];
      x[l] += h4.x*w0 + h4.y*w1 + h4.z*w2 + h4.w*w3;
    }
  }
  __syncthreads();

  // ---- P13: final rmsnorm ----
  #pragma unroll
  for(int l=0;l<9;l++) S[O_RED + l*128 + t] = x[l]*x[l];
  __syncthreads();
  if(t < 9){
    float s = 0.f;
    for(int i=0;i<128;i++) s += S[O_RED + t*128 + i];
    S[O_SS + t] = sqrtf(s/128.f + 1e-6f);
  }
  __syncthreads();

  // ---- P14: apply precomputed film + store (f32) ----
  {
    float g1c = g1[t];
    int b = n >> 10;
    #pragma unroll
    for(int l=0;l<9;l++){
      int j = l*128 + t;
      float w  = filmG[b*2304 + j];
      float bi = filmG[b*2304 + 1152 + j];
      float y = x[l]/S[O_SS + l]*g1c;
      out[12288 + (size_t)n*1152 + j] = y*w + bi;
    }
  }
}

// ---------- K2: coords (exact f32 copy) + batch (= n>>10, f32) ----------
__global__ __launch_bounds__(256) void k_copy(const float* __restrict__ coord,
                                              float* __restrict__ out){
  int i = blockIdx.x*256 + threadIdx.x;
  if(i < 12288) out[i] = coord[i];
  int n = i - 12288;
  if(n >= 0 && n < 4096) out[12288 + 4718592 + n] = (float)(n >> 10);
}

extern "C" void kernel_launch(void* const* d_in, const int* in_sizes, int n_in,
                              void* d_out, int out_size, void* d_ws, size_t ws_size,
                              hipStream_t stream) {
  const float* coord = (const float*)d_in[0];
  const float* emb   = (const float*)d_in[1];
  const float* cond  = (const float*)d_in[3];
  const float* We1   = (const float*)d_in[4];
  const float* be1   = (const float*)d_in[5];
  const float* We2   = (const float*)d_in[6];
  const float* be2   = (const float*)d_in[7];
  const float* Wsrc  = (const float*)d_in[8];
  const float* Wdst  = (const float*)d_in[9];
  const float* wa    = (const float*)d_in[10];
  const float* Wv    = (const float*)d_in[11];
  const float* Wo    = (const float*)d_in[12];
  const float* g1    = (const float*)d_in[13];
  const float* g2    = (const float*)d_in[14];
  const float* Wg    = (const float*)d_in[15];
  const float* Wf1   = (const float*)d_in[16];
  const float* Wf2   = (const float*)d_in[17];
  const float* Wfilm = (const float*)d_in[18];
  const float* bfilm = (const float*)d_in[19];

  float* outf  = (float*)d_out;
  float* filmG = (float*)d_ws;   // 4 x 2304 f32 = 36,864 B

  k_film<<<dim3(9,4), 256, 0, stream>>>(cond, Wfilm, bfilm, filmG);
  k_node<<<NNODE, 128, 0, stream>>>(coord, emb,
                                    We1, be1, We2, be2, Wsrc, Wdst, wa,
                                    Wv, Wo, g1, g2, Wg, Wf1, Wf2,
                                    filmG, outf);
  k_copy<<<64, 256, 0, stream>>>(coord, outf);
}

// Round 9
// 1445.201 us; speedup vs baseline: 1.1012x; 1.0006x over previous
//
#include <hip/hip_runtime.h>
#include <hip/hip_bf16.h>

#define NNODE 4096
#define NPB   1024
#define KNEI  16

__device__ __forceinline__ float siluf(float x){ return x / (1.0f + expf(-x)); }

// ---------------- LDS layout (floats), peak 7680 floats = 30720 B ----------------
// Region A: 0..3072    CRD(P0-1) | ES/ED/QD/LG/SX(P2-5) | RB(P6-7) | XS2(P9) | RED(P10,P13) | HF(P11-12)
// Region B: 3072..5184 HD(P7-8) | AG(P9-10)
// Region C: 5184..7296 EH(P8-9) | HL(P10-11)
// Region D: 7296..7680 AT, RR, KI, KD, SS (long-lived smalls)
#define O_CRD  0
#define O_ES   0
#define O_ED   2112
#define O_QD   2240
#define O_LG   2304
#define O_SX   2432
#define O_RB   0
#define O_XS   0     /* 2x9 rows, stride 132 = 2376 */
#define O_RED  0
#define O_HF   0
#define O_HD   3072
#define O_AG   3072
#define O_EH   5184
#define O_HL   5184
#define O_AT   7296  /* 128 */
#define O_RR   7424  /* 192: 16 x (R[9], len, valid, pad) */
#define O_KI   7616  /* 16 ints */
#define O_KD   7632  /* 16 */
#define O_SS   7652  /* 16 */

// ---------- K0: film = mish(cond) @ Wfilm + bfilm -> d_ws (4 x 2304 f32) ----------
__global__ __launch_bounds__(256) void k_film(const float* __restrict__ cond,
                                              const float* __restrict__ Wfilm,
                                              const float* __restrict__ bfilm,
                                              float* __restrict__ filmG){
  __shared__ float mL[256];
  int b = blockIdx.y;
  int t = threadIdx.x;
  int j = blockIdx.x*256 + t;
  float x = cond[b*256 + t];
  float sp = fmaxf(x, 0.f) + log1pf(expf(-fabsf(x)));
  mL[t] = x * tanhf(sp);
  __syncthreads();
  if(j >= 2304) return;
  float acc = bfilm[j];
  for(int i=0;i<256;i++) acc += mL[i] * Wfilm[i*2304 + j];
  filmG[b*2304 + j] = acc;
}

__global__ __launch_bounds__(128, 4) void k_node(
    const float* __restrict__ coord,
    const float* __restrict__ emb,
    const float* __restrict__ We1, const float* __restrict__ be1,
    const float* __restrict__ We2, const float* __restrict__ be2,
    const float* __restrict__ Wsrc, const float* __restrict__ Wdst,
    const float* __restrict__ wa,
    const float* __restrict__ Wv, const float* __restrict__ Wo,
    const float* __restrict__ g1, const float* __restrict__ g2,
    const float* __restrict__ Wg, const float* __restrict__ Wf1,
    const float* __restrict__ Wf2,
    const float* __restrict__ filmG,
    float* __restrict__ out){
  __shared__ __align__(16) float S[7680];
  int* Si = (int*)S;
  const int n = blockIdx.x;
  const int t = threadIdx.x;
  const int base = n & ~(NPB - 1);
  const int self = n - base;

  // ---- P0: stage coords; wave 0 does the full KNN (no barriers inside) ----
  for(int idx = t; idx < 3072; idx += 128) S[O_CRD + idx] = coord[base*3 + idx];
  __syncthreads();
  const float cx = S[O_CRD + self*3+0];
  const float cy = S[O_CRD + self*3+1];
  const float cz = S[O_CRD + self*3+2];
  if(t < 64){
    float d2a[16]; int ida[16];
    for(int q=0;q<16;q++){
      int j = t + q*64;
      float dx = __fsub_rn(S[O_CRD + j*3+0], cx);
      float dy = __fsub_rn(S[O_CRD + j*3+1], cy);
      float dz = __fsub_rn(S[O_CRD + j*3+2], cz);
      float d2 = __fadd_rn(__fadd_rn(__fmul_rn(dx,dx), __fmul_rn(dy,dy)), __fmul_rn(dz,dz));
      if(j == self) d2 = 3e38f;
      d2a[q] = d2; ida[q] = j;
    }
    for(int r=0;r<16;r++){
      float bd = d2a[0]; int bi = ida[0];
      for(int q=1;q<16;q++){
        bool bet = (d2a[q] < bd) || (d2a[q] == bd && ida[q] < bi);
        if(bet){ bd = d2a[q]; bi = ida[q]; }
      }
      for(int s=1;s<64;s<<=1){
        float od = __shfl_xor(bd, s, 64);
        int   oi = __shfl_xor(bi, s, 64);
        bool bet = (od < bd) || (od == bd && oi < bi);
        if(bet){ bd = od; bi = oi; }
      }
      if(t == 0){ Si[O_KI + r] = bi; S[O_KD + r] = bd; }
      for(int q=0;q<16;q++) if(ida[q] == bi) d2a[q] = 3e38f;
    }
  }
  __syncthreads();

  // ---- P1: edge geometry (R, len, valid), threads 0..15 ----
  if(t < 16){
    int ls = Si[O_KI + t];
    float vx = __fsub_rn(S[O_CRD + ls*3+0], cx);
    float vy = __fsub_rn(S[O_CRD + ls*3+1], cy);
    float vz = __fsub_rn(S[O_CRD + ls*3+2], cz);
    float nrm = __fsqrt_rn(S[O_KD + t]);
    float den = __fadd_rn(nrm, 1e-12f);
    float nx0 = vx / den, nx1 = vy / den, nx2 = vz / den;
    float rx, ry, rz;
    if(fabsf(nx0) < 0.9f){ rx=1.f; ry=0.f; rz=0.f; } else { rx=0.f; ry=1.f; rz=0.f; }
    float zx = __fsub_rn(__fmul_rn(nx1,rz), __fmul_rn(nx2,ry));
    float zy = __fsub_rn(__fmul_rn(nx2,rx), __fmul_rn(nx0,rz));
    float zz = __fsub_rn(__fmul_rn(nx0,ry), __fmul_rn(nx1,rx));
    float zs = __fadd_rn(__fadd_rn(__fmul_rn(zx,zx), __fmul_rn(zy,zy)), __fmul_rn(zz,zz));
    float zn = __fadd_rn(__fsqrt_rn(zs), 1e-12f);
    zx = zx / zn; zy = zy / zn; zz = zz / zn;
    float yx = __fsub_rn(__fmul_rn(zy,nx2), __fmul_rn(zz,nx1));
    float yy = __fsub_rn(__fmul_rn(zz,nx0), __fmul_rn(zx,nx2));
    float yz = __fsub_rn(__fmul_rn(zx,nx1), __fmul_rn(zy,nx0));
    float* R = &S[O_RR + t*12];
    R[0]=zx; R[1]=zy; R[2]=zz;
    R[3]=nx0; R[4]=nx1; R[5]=nx2;
    R[6]=yx; R[7]=yy; R[8]=yz;
    R[9]=nrm;
    R[10]=(nrm <= 3.0f) ? 1.0f : 0.0f;
  }
  __syncthreads();

  // ---- P2: stage src l=0 rows (f4) + dst l=0 row ----
  for(int it=0; it<4; it++){
    int vid = it*128 + t;          // 512 float4 = 16 edges x 32 vec
    int e = vid >> 5, c4 = vid & 31;
    int src = base + Si[O_KI + e];
    *(float4*)&S[O_ES + e*132 + c4*4] = *(const float4*)&emb[(size_t)src*1152 + c4*4];
  }
  S[O_ED + t] = emb[(size_t)n*1152 + t];
  __syncthreads();

  // ---- P3: qd = dst0 @ Wdst (threads 0..63) ----
  if(t < 64){
    float acc = 0.f;
    for(int c4=0;c4<32;c4++){
      float4 ev = *(const float4*)&S[O_ED + c4*4];
      acc += ev.x * Wdst[(c4*4+0)*64 + t];
      acc += ev.y * Wdst[(c4*4+1)*64 + t];
      acc += ev.z * Wdst[(c4*4+2)*64 + t];
      acc += ev.w * Wdst[(c4*4+3)*64 + t];
    }
    S[O_QD + t] = acc;
  }
  __syncthreads();

  // ---- P4: logits (wave wv handles edges wv*8..wv*8+7) ----
  {
    int wv = t >> 6;
    int ha = t & 63;
    float acc8[8];
    #pragma unroll
    for(int k=0;k<8;k++) acc8[k] = 0.f;
    for(int c4=0;c4<32;c4++){
      float w0 = Wsrc[(c4*4+0)*64 + ha];
      float w1 = Wsrc[(c4*4+1)*64 + ha];
      float w2 = Wsrc[(c4*4+2)*64 + ha];
      float w3 = Wsrc[(c4*4+3)*64 + ha];
      #pragma unroll
      for(int k=0;k<8;k++){
        float4 es = *(const float4*)&S[O_ES + (wv*8+k)*132 + c4*4];
        acc8[k] += es.x*w0 + es.y*w1 + es.z*w2 + es.w*w3;
      }
    }
    float qd = S[O_QD + ha];
    float wav = wa[ha];
    #pragma unroll
    for(int k=0;k<8;k++){
      float s = siluf(acc8[k] + qd) * wav;
      s += __shfl_xor(s, 1, 64);
      s += __shfl_xor(s, 2, 64);
      s += __shfl_xor(s, 4, 64);
      if((ha & 7) == 0){
        int e = wv*8 + k;
        float v = S[O_RR + e*12 + 10];
        S[O_LG + e*8 + (ha>>3)] = (v > 0.5f) ? s : -1e9f;
      }
    }
  }
  __syncthreads();

  // ---- P5: softmax per head over 16 edges ----
  if(t < 8){
    float m = -3e38f;
    for(int r=0;r<16;r++) m = fmaxf(m, S[O_LG + r*8 + t]);
    S[O_SX + t] = m;
  }
  __syncthreads();
  {
    float ex = expf(S[O_LG + t] - S[O_SX + (t & 7)]);
    __syncthreads();
    S[O_LG + t] = ex;
    __syncthreads();
    if(t < 8){
      float d = 0.f;
      for(int r=0;r<16;r++) d += S[O_LG + r*8 + t];
      S[O_SX + 8 + t] = d;
    }
    __syncthreads();
    S[O_AT + t] = ex / (S[O_SX + 8 + (t & 7)] + 1e-9f);
  }
  __syncthreads();

  // ---- P6: rbf (overwrites ES region) ----
  {
    const float step = 3.0f/127.0f;
    const float sigma = 3.0f/128.0f;
    for(int idx = t; idx < 2048; idx += 128){
      int e = idx >> 7, i = idx & 127;
      float d = (S[O_RR + e*12 + 9] - step*(float)i) / sigma;
      S[O_RB + e*132 + i] = expf(-0.5f*d*d);
    }
  }
  __syncthreads();

  // ---- P7: hid = silu(rbf @ We1 + b1); thread t = column, all 16 edges ----
  {
    float acc16[16];
    #pragma unroll
    for(int e=0;e<16;e++) acc16[e] = 0.f;
    for(int i4=0;i4<32;i4++){
      float w0 = We1[(i4*4+0)*128 + t];
      float w1 = We1[(i4*4+1)*128 + t];
      float w2 = We1[(i4*4+2)*128 + t];
      float w3 = We1[(i4*4+3)*128 + t];
      #pragma unroll
      for(int e=0;e<16;e++){
        float4 r = *(const float4*)&S[O_RB + e*132 + i4*4];
        acc16[e] += r.x*w0 + r.y*w1 + r.z*w2 + r.w*w3;
      }
    }
    float b = be1[t];
    #pragma unroll
    for(int e=0;e<16;e++) S[O_HD + e*132 + t] = siluf(acc16[e] + b);
  }
  __syncthreads();

  // ---- P8: eh = hid @ We2 + b2 ----
  {
    float acc16[16];
    #pragma unroll
    for(int e=0;e<16;e++) acc16[e] = 0.f;
    for(int i4=0;i4<32;i4++){
      float w0 = We2[(i4*4+0)*128 + t];
      float w1 = We2[(i4*4+1)*128 + t];
      float w2 = We2[(i4*4+2)*128 + t];
      float w3 = We2[(i4*4+3)*128 + t];
      #pragma unroll
      for(int e=0;e<16;e++){
        float4 h = *(const float4*)&S[O_HD + e*132 + i4*4];
        acc16[e] += h.x*w0 + h.y*w1 + h.z*w2 + h.w*w3;
      }
    }
    float b = be2[t];
    #pragma unroll
    for(int e=0;e<16;e++) S[O_EH + e*132 + t] = acc16[e] + b;
  }
  __syncthreads();

  // ---- P9: message passing, 8 chunks of 2 edges; Wv loaded once per chunk ----
  float acc[9];
  #pragma unroll
  for(int l=0;l<9;l++) acc[l] = 0.f;
  for(int ch=0; ch<8; ch++){
    // stage rotated xs for 2 edges (rows: e2*9 + l, stride 132)
    #pragma unroll
    for(int e2=0; e2<2; e2++){
      int e = ch*2 + e2;
      int src = base + Si[O_KI + e];
      float R0=S[O_RR+e*12+0],R1=S[O_RR+e*12+1],R2=S[O_RR+e*12+2];
      float R3=S[O_RR+e*12+3],R4=S[O_RR+e*12+4],R5=S[O_RR+e*12+5];
      float R6=S[O_RR+e*12+6],R7=S[O_RR+e*12+7],R8=S[O_RR+e*12+8];
      float a[9];
      #pragma unroll
      for(int l=0;l<9;l++) a[l] = emb[(size_t)src*1152 + l*128 + t];
      S[O_XS + (e2*9+0)*132 + t] = a[0];
      S[O_XS + (e2*9+1)*132 + t] = R0*a[1] + R1*a[2] + R2*a[3];
      S[O_XS + (e2*9+2)*132 + t] = R3*a[1] + R4*a[2] + R5*a[3];
      S[O_XS + (e2*9+3)*132 + t] = R6*a[1] + R7*a[2] + R8*a[3];
      #pragma unroll
      for(int l=4;l<9;l++) S[O_XS + (e2*9+l)*132 + t] = a[l];
    }
    __syncthreads();
    float tmp[2][9];
    #pragma unroll
    for(int e2=0;e2<2;e2++)
      #pragma unroll
      for(int l=0;l<9;l++) tmp[e2][l] = 0.f;
    for(int i4=0;i4<32;i4++){
      float w0 = Wv[(i4*4+0)*128 + t];
      float w1 = Wv[(i4*4+1)*128 + t];
      float w2 = Wv[(i4*4+2)*128 + t];
      float w3 = Wv[(i4*4+3)*128 + t];
      #pragma unroll
      for(int e2=0;e2<2;e2++){
        #pragma unroll
        for(int l=0;l<9;l++){
          float4 x4 = *(const float4*)&S[O_XS + (e2*9+l)*132 + i4*4];
          tmp[e2][l] += x4.x*w0 + x4.y*w1 + x4.z*w2 + x4.w*w3;
        }
      }
    }
    #pragma unroll
    for(int e2=0;e2<2;e2++){
      int e = ch*2 + e2;
      float R0=S[O_RR+e*12+0],R1=S[O_RR+e*12+1],R2=S[O_RR+e*12+2];
      float R3=S[O_RR+e*12+3],R4=S[O_RR+e*12+4],R5=S[O_RR+e*12+5];
      float R6=S[O_RR+e*12+6],R7=S[O_RR+e*12+7],R8=S[O_RR+e*12+8];
      float sc = S[O_EH + e*132 + t] * S[O_AT + e*8 + (t>>4)];
      float t0 = tmp[e2][0]*sc;
      float t1 = tmp[e2][1]*sc;
      float t2 = tmp[e2][2]*sc;
      float t3 = tmp[e2][3]*sc;
      acc[0] += t0;
      acc[1] += R0*t1 + R3*t2 + R6*t3;
      acc[2] += R1*t1 + R4*t2 + R7*t3;
      acc[3] += R2*t1 + R5*t2 + R8*t3;
      #pragma unroll
      for(int l=4;l<9;l++) acc[l] += tmp[e2][l]*sc;
    }
    __syncthreads();
  }
  #pragma unroll
  for(int l=0;l<9;l++) S[O_AG + l*128 + t] = acc[l];
  __syncthreads();

  // ---- P10: x = emb + agg @ Wo ; rmsnorm*g2 -> HL ----
  float x[9];
  #pragma unroll
  for(int l=0;l<9;l++) x[l] = 0.f;
  for(int i4=0;i4<32;i4++){
    float w0 = Wo[(i4*4+0)*128 + t];
    float w1 = Wo[(i4*4+1)*128 + t];
    float w2 = Wo[(i4*4+2)*128 + t];
    float w3 = Wo[(i4*4+3)*128 + t];
    #pragma unroll
    for(int l=0;l<9;l++){
      float4 a4 = *(const float4*)&S[O_AG + l*128 + i4*4];
      x[l] += a4.x*w0 + a4.y*w1 + a4.z*w2 + a4.w*w3;
    }
  }
  #pragma unroll
  for(int l=0;l<9;l++){
    x[l] += emb[(size_t)n*1152 + l*128 + t];
    S[O_RED + l*128 + t] = x[l]*x[l];
  }
  __syncthreads();
  if(t < 9){
    float s = 0.f;
    for(int i=0;i<128;i++) s += S[O_RED + t*128 + i];
    S[O_SS + t] = sqrtf(s/128.f + 1e-6f);
  }
  __syncthreads();
  {
    float g2c = g2[t];
    #pragma unroll
    for(int l=0;l<9;l++) S[O_HL + l*132 + t] = x[l]/S[O_SS + l]*g2c;
  }
  __syncthreads();

  // ---- P11: gate + hf = (h @ Wf1)*gate -> HF ----
  {
    float ga0 = 0.f, ga1 = 0.f;
    for(int c4=0;c4<32;c4++){
      float4 h4 = *(const float4*)&S[O_HL + c4*4];
      ga0 += h4.x*Wg[(c4*4+0)*256 + t] + h4.y*Wg[(c4*4+1)*256 + t]
           + h4.z*Wg[(c4*4+2)*256 + t] + h4.w*Wg[(c4*4+3)*256 + t];
      ga1 += h4.x*Wg[(c4*4+0)*256 + t + 128] + h4.y*Wg[(c4*4+1)*256 + t + 128]
           + h4.z*Wg[(c4*4+2)*256 + t + 128] + h4.w*Wg[(c4*4+3)*256 + t + 128];
    }
    float gate0 = siluf(ga0), gate1 = siluf(ga1);
    float f0[9], f1[9];
    #pragma unroll
    for(int l=0;l<9;l++){ f0[l]=0.f; f1[l]=0.f; }
    for(int c4=0;c4<32;c4++){
      float w0a = Wf1[(c4*4+0)*256 + t], w0b = Wf1[(c4*4+0)*256 + t + 128];
      float w1a = Wf1[(c4*4+1)*256 + t], w1b = Wf1[(c4*4+1)*256 + t + 128];
      float w2a = Wf1[(c4*4+2)*256 + t], w2b = Wf1[(c4*4+2)*256 + t + 128];
      float w3a = Wf1[(c4*4+3)*256 + t], w3b = Wf1[(c4*4+3)*256 + t + 128];
      #pragma unroll
      for(int l=0;l<9;l++){
        float4 h4 = *(const float4*)&S[O_HL + l*132 + c4*4];
        f0[l] += h4.x*w0a + h4.y*w1a + h4.z*w2a + h4.w*w3a;
        f1[l] += h4.x*w0b + h4.y*w1b + h4.z*w2b + h4.w*w3b;
      }
    }
    __syncthreads();   // HL reads done before HF overwrites region A
    #pragma unroll
    for(int l=0;l<9;l++){
      S[O_HF + l*260 + t]       = f0[l]*gate0;
      S[O_HF + l*260 + t + 128] = f1[l]*gate1;
    }
  }
  __syncthreads();

  // ---- P12: x += hf @ Wf2 ----
  for(int f4=0;f4<64;f4++){
    float w0 = Wf2[(f4*4+0)*128 + t];
    float w1 = Wf2[(f4*4+1)*128 + t];
    float w2 = Wf2[(f4*4+2)*128 + t];
    float w3 = Wf2[(f4*4+3)*128 + t];
    #pragma unroll
    for(int l=0;l<9;l++){
      float4 h4 = *(const float4*)&S[O_HF + l*260 + f4*4];
      x[l] += h4.x*w0 + h4.y*w1 + h4.z*w2 + h4.w*w3;
    }
  }
  __syncthreads();

  // ---- P13: final rmsnorm ----
  #pragma unroll
  for(int l=0;l<9;l++) S[O_RED + l*128 + t] = x[l]*x[l];
  __syncthreads();
  if(t < 9){
    float s = 0.f;
    for(int i=0;i<128;i++) s += S[O_RED + t*128 + i];
    S[O_SS + t] = sqrtf(s/128.f + 1e-6f);
  }
  __syncthreads();

  // ---- P14: apply precomputed film + store (f32) ----
  {
    float g1c = g1[t];
    int b = n >> 10;
    #pragma unroll
    for(int l=0;l<9;l++){
      int j = l*128 + t;
      float w  = filmG[b*2304 + j];
      float bi = filmG[b*2304 + 1152 + j];
      float y = x[l]/S[O_SS + l]*g1c;
      out[12288 + (size_t)n*1152 + j] = y*w + bi;
    }
  }
}

// ---------- K2: coords (exact f32 copy) + batch (= n>>10, f32) ----------
__global__ __launch_bounds__(256) void k_copy(const float* __restrict__ coord,
                                              float* __restrict__ out){
  int i = blockIdx.x*256 + threadIdx.x;
  if(i < 12288) out[i] = coord[i];
  int n = i - 12288;
  if(n >= 0 && n < 4096) out[12288 + 4718592 + n] = (float)(n >> 10);
}

extern "C" void kernel_launch(void* const* d_in, const int* in_sizes, int n_in,
                              void* d_out, int out_size, void* d_ws, size_t ws_size,
                              hipStream_t stream) {
  const float* coord = (const float*)d_in[0];
  const float* emb   = (const float*)d_in[1];
  const float* cond  = (const float*)d_in[3];
  const float* We1   = (const float*)d_in[4];
  const float* be1   = (const float*)d_in[5];
  const float* We2   = (const float*)d_in[6];
  const float* be2   = (const float*)d_in[7];
  const float* Wsrc  = (const float*)d_in[8];
  const float* Wdst  = (const float*)d_in[9];
  const float* wa    = (const float*)d_in[10];
  const float* Wv    = (const float*)d_in[11];
  const float* Wo    = (const float*)d_in[12];
  const float* g1    = (const float*)d_in[13];
  const float* g2    = (const float*)d_in[14];
  const float* Wg    = (const float*)d_in[15];
  const float* Wf1   = (const float*)d_in[16];
  const float* Wf2   = (const float*)d_in[17];
  const float* Wfilm = (const float*)d_in[18];
  const float* bfilm = (const float*)d_in[19];

  float* outf  = (float*)d_out;
  float* filmG = (float*)d_ws;   // 4 x 2304 f32 = 36,864 B

  k_film<<<dim3(9,4), 256, 0, stream>>>(cond, Wfilm, bfilm, filmG);
  k_node<<<NNODE, 128, 0, stream>>>(coord, emb,
                                    We1, be1, We2, be2, Wsrc, Wdst, wa,
                                    Wv, Wo, g1, g2, Wg, Wf1, Wf2,
                                    filmG, outf);
  k_copy<<<64, 256, 0, stream>>>(coord, outf);
}